// Round 3
// baseline (1018.298 us; speedup 1.0000x reference)
//
#include <hip/hip_runtime.h>
#include <cstdint>
#include <cstddef>

// Problem constants
#define SEQ   2048
#define HID   1024
#define NBAT  64
#define NSEG  4
#define NNODE 7
#define TCHUNK 128

typedef __attribute__((ext_vector_type(8))) short short8;     // 8 bf16 (4 VGPR) MFMA A/B frag
typedef __attribute__((ext_vector_type(8))) unsigned short ushort8;
typedef __attribute__((ext_vector_type(4))) float f32x4;      // MFMA C/D frag

__device__ __forceinline__ float gelu_f(float x) {
  return 0.5f * x * (1.0f + erff(x * 0.7071067811865476f));
}

// split fp32 -> bf16 hi (trunc) + bf16 lo (trunc of remainder); hh+hl+lh MFMA
// reconstructs ~17 mantissa bits (products exact in fp32 accumulate).
__device__ __forceinline__ void split1(float f, unsigned short& h, unsigned short& l) {
  unsigned u = __float_as_uint(f);
  h = (unsigned short)(u >> 16);
  float hf = __uint_as_float(u & 0xFFFF0000u);
  l = (unsigned short)(__float_as_uint(f - hf) >> 16);
}

__device__ __forceinline__ void split_f32x8(const float4 x0, const float4 x1, float s,
                                            short8& hi, short8& lo) {
  float v[8] = {x0.x * s, x0.y * s, x0.z * s, x0.w * s,
                x1.x * s, x1.y * s, x1.z * s, x1.w * s};
  #pragma unroll
  for (int j = 0; j < 8; ++j) {
    unsigned short h, l;
    split1(v[j], h, l);
    hi[j] = (short)h;
    lo[j] = (short)l;
  }
}

// ---------------------------------------------------------------------------
// Weight prep: W[K][1024] fp32  ->  WT_hi[1024][K], WT_lo[1024][K] bf16 planes.
// 64x64 tile transpose via LDS. Grid (32,16,4): z selects matrix, extra x exit.
// ---------------------------------------------------------------------------
__global__ __launch_bounds__(256) void wprep_kernel(
    const float* __restrict__ W1, const float* __restrict__ W2,
    const float* __restrict__ Wm1, const float* __restrict__ Wm2,
    unsigned short* __restrict__ o1h, unsigned short* __restrict__ o1l,
    unsigned short* __restrict__ o2h, unsigned short* __restrict__ o2l,
    unsigned short* __restrict__ om1h, unsigned short* __restrict__ om1l,
    unsigned short* __restrict__ om2h, unsigned short* __restrict__ om2l)
{
  const float* src; unsigned short *dh, *dl; int K;
  switch (blockIdx.z) {
    case 0: src = W1;  dh = o1h;  dl = o1l;  K = 1024; break;
    case 1: src = W2;  dh = o2h;  dl = o2l;  K = 1024; break;
    case 2: src = Wm1; dh = om1h; dl = om1l; K = 2048; break;
    default: src = Wm2; dh = om2h; dl = om2l; K = 1024; break;
  }
  const int k0 = blockIdx.x * 64;
  if (k0 >= K) return;
  const int n0 = blockIdx.y * 64;

  __shared__ float T[64][65];
  const int t = threadIdx.x;
  const int lr = t >> 4, lc = (t & 15) * 4;
  #pragma unroll
  for (int i = 0; i < 4; ++i) {
    int kk = lr + i * 16;
    float4 v = *(const float4*)(src + (size_t)(k0 + kk) * 1024 + n0 + lc);
    T[kk][lc + 0] = v.x; T[kk][lc + 1] = v.y;
    T[kk][lc + 2] = v.z; T[kk][lc + 3] = v.w;
  }
  __syncthreads();

  const int n = t >> 2, kc = (t & 3) * 16;
  ushort8 h0, h1, l0, l1;
  #pragma unroll
  for (int j = 0; j < 8; ++j) {
    unsigned short h, l;
    split1(T[kc + j][n], h, l);
    h0[j] = h; l0[j] = l;
    split1(T[kc + 8 + j][n], h, l);
    h1[j] = h; l1[j] = l;
  }
  size_t o = (size_t)(n0 + n) * K + k0 + kc;
  *(ushort8*)(dh + o)     = h0;
  *(ushort8*)(dh + o + 8) = h1;
  *(ushort8*)(dl + o)     = l0;
  *(ushort8*)(dl + o + 8) = l1;
}

// ---------------------------------------------------------------------------
// Ragged segment-sum pooling (unchanged; memory-roofline-bound).
// ---------------------------------------------------------------------------
__global__ __launch_bounds__(256) void pool_kernel(
    const float* __restrict__ states, const int* __restrict__ boundaries,
    const int* __restrict__ lengths, float* __restrict__ pooled_sum)
{
  const int tc = blockIdx.x, b = blockIdx.y;
  const int tid = threadIdx.x;
  int bnd[5];
  bnd[0] = boundaries[b * 4 + 0];
  bnd[1] = boundaries[b * 4 + 1];
  bnd[2] = boundaries[b * 4 + 2];
  bnd[3] = boundaries[b * 4 + 3];
  bnd[4] = lengths[b];
  const int clo = tc * TCHUNK, chi = clo + TCHUNK;
  const float4* S = (const float4*)(states + (size_t)b * SEQ * HID);

  #pragma unroll
  for (int s = 0; s < NSEG; ++s) {
    int lo = bnd[s]     > clo ? bnd[s]     : clo;
    int hi = bnd[s + 1] < chi ? bnd[s + 1] : chi;
    if (lo >= hi) continue;
    float4 acc = make_float4(0.f, 0.f, 0.f, 0.f);
    int t = lo;
    for (; t + 4 <= hi; t += 4) {
      float4 v0 = S[(size_t)(t + 0) * (HID / 4) + tid];
      float4 v1 = S[(size_t)(t + 1) * (HID / 4) + tid];
      float4 v2 = S[(size_t)(t + 2) * (HID / 4) + tid];
      float4 v3 = S[(size_t)(t + 3) * (HID / 4) + tid];
      acc.x += (v0.x + v1.x) + (v2.x + v3.x);
      acc.y += (v0.y + v1.y) + (v2.y + v3.y);
      acc.z += (v0.z + v1.z) + (v2.z + v3.z);
      acc.w += (v0.w + v1.w) + (v2.w + v3.w);
    }
    for (; t < hi; ++t) {
      float4 v = S[(size_t)t * (HID / 4) + tid];
      acc.x += v.x; acc.y += v.y; acc.z += v.z; acc.w += v.w;
    }
    float* dst = pooled_sum + (size_t)(b * NSEG + s) * HID + tid * 4;
    atomicAdd(dst + 0, acc.x);
    atomicAdd(dst + 1, acc.y);
    atomicAdd(dst + 2, acc.z);
    atomicAdd(dst + 3, acc.w);
  }
}

// ---------------------------------------------------------------------------
// MFMA split-bf16 GEMM, no LDS: C[M x 1024] = epi(A[M x K] @ W[K x 1024] + b)
// Block = 64x64 tile, 4 waves in 2x2; wave does 2x2 16x16 tiles.
// Frags (verified layouts): A[m=l&15][k=q*8+j], B[k=q*8+j][n=l&15],
// C/D row=q*4+reg, col=l&15  (q = lane>>4).
// AMODE: 1 = fp32 A rows * rowscale, split in-loop (G1, pooled)
//        0 = pre-split A planes (Ah/Al)
//        2 = gather concat(node[lc],node[rc]) from pre-split node planes
// EPI:   0 = gelu -> split planes Ch/Cl
//        1 = leaf scatter -> node planes
//        2 = merge scatter -> node planes
//        3 = root + topology hash + shape_embed -> fp32 out
// ---------------------------------------------------------------------------
template<int AMODE, int EPI, int KDIM>
__global__ __launch_bounds__(256) void mfma_gemm(
    const float* __restrict__ Af,
    const unsigned short* __restrict__ Ah, const unsigned short* __restrict__ Al,
    const unsigned short* __restrict__ Bh, const unsigned short* __restrict__ Bl,
    const float* __restrict__ bias,
    unsigned short* __restrict__ Ch, unsigned short* __restrict__ Cl,
    float* __restrict__ Cf,
    const int* __restrict__ boundaries, const int* __restrict__ lengths,
    const int* __restrict__ leaf_order, const int* __restrict__ active,
    const int* __restrict__ is_leaf, const int* __restrict__ depth,
    const int* __restrict__ left_child, const int* __restrict__ right_child,
    const float* __restrict__ dembed, const float* __restrict__ sembed,
    const unsigned short* __restrict__ nodeH, const unsigned short* __restrict__ nodeL,
    int nodeA, int nodeB)
{
  const int tid  = threadIdx.x;
  const int wave = tid >> 6, lane = tid & 63;
  const int wm = (wave >> 1) * 32, wn = (wave & 1) * 32;
  const int l15 = lane & 15, q = lane >> 4;
  const int m0 = blockIdx.y * 64, n0 = blockIdx.x * 64;
  const int kq0 = q * 8;

  f32x4 acc[2][2] = {};

  int mrow[2];
  mrow[0] = m0 + wm + l15;
  mrow[1] = mrow[0] + 16;

  const float* arow[2] = {nullptr, nullptr};
  const unsigned short *ahrow[2], *alrow[2];
  const unsigned short *aLh[2], *aLl[2], *aRh[2], *aRl[2];
  float ainv[2] = {1.0f, 1.0f};

  #pragma unroll
  for (int mt = 0; mt < 2; ++mt) {
    if (AMODE == 1) {
      int b = mrow[mt] >> 2, s = mrow[mt] & 3;
      int bs = boundaries[b * 4 + s];
      int bn = (s < 3) ? boundaries[b * 4 + s + 1] : lengths[b];
      ainv[mt] = 1.0f / fmaxf((float)(bn - bs), 1.0f);
      arow[mt] = Af + (size_t)mrow[mt] * KDIM;
    } else if (AMODE == 0) {
      ahrow[mt] = Ah + (size_t)mrow[mt] * KDIM;
      alrow[mt] = Al + (size_t)mrow[mt] * KDIM;
    } else {
      int node = (mrow[mt] >> 6) ? nodeB : nodeA;
      int b = mrow[mt] & 63;
      int lc = left_child[node], rc = right_child[node];
      aLh[mt] = nodeH + (size_t)(b * NNODE + lc) * 1024;
      aLl[mt] = nodeL + (size_t)(b * NNODE + lc) * 1024;
      aRh[mt] = nodeH + (size_t)(b * NNODE + rc) * 1024;
      aRl[mt] = nodeL + (size_t)(b * NNODE + rc) * 1024;
    }
  }

  const unsigned short *brh[2], *brl[2];
  #pragma unroll
  for (int nt = 0; nt < 2; ++nt) {
    int n = n0 + wn + nt * 16 + l15;
    brh[nt] = Bh + (size_t)n * KDIM;
    brl[nt] = Bl + (size_t)n * KDIM;
  }

  #pragma unroll 4
  for (int k0 = 0; k0 < KDIM; k0 += 32) {
    const int kq = k0 + kq0;
    short8 ah[2], al[2], bh[2], bl[2];
    #pragma unroll
    for (int mt = 0; mt < 2; ++mt) {
      if (AMODE == 1) {
        const float* rp = arow[mt] + kq;
        float4 x0 = *(const float4*)rp;
        float4 x1 = *(const float4*)(rp + 4);
        split_f32x8(x0, x1, ainv[mt], ah[mt], al[mt]);
      } else if (AMODE == 0) {
        ah[mt] = *(const short8*)(ahrow[mt] + kq);
        al[mt] = *(const short8*)(alrow[mt] + kq);
      } else {
        const bool L = (k0 < 1024);
        const int c = kq & 1023;
        ah[mt] = *(const short8*)((L ? aLh[mt] : aRh[mt]) + c);
        al[mt] = *(const short8*)((L ? aLl[mt] : aRl[mt]) + c);
      }
    }
    #pragma unroll
    for (int nt = 0; nt < 2; ++nt) {
      bh[nt] = *(const short8*)(brh[nt] + kq);
      bl[nt] = *(const short8*)(brl[nt] + kq);
    }
    #pragma unroll
    for (int mt = 0; mt < 2; ++mt)
      #pragma unroll
      for (int nt = 0; nt < 2; ++nt) {
        acc[mt][nt] = __builtin_amdgcn_mfma_f32_16x16x32_bf16(ah[mt], bh[nt], acc[mt][nt], 0, 0, 0);
        acc[mt][nt] = __builtin_amdgcn_mfma_f32_16x16x32_bf16(ah[mt], bl[nt], acc[mt][nt], 0, 0, 0);
        acc[mt][nt] = __builtin_amdgcn_mfma_f32_16x16x32_bf16(al[mt], bh[nt], acc[mt][nt], 0, 0, 0);
      }
  }

  // ---- epilogue ----
  #pragma unroll
  for (int mt = 0; mt < 2; ++mt) {
    #pragma unroll
    for (int nt = 0; nt < 2; ++nt) {
      const int n = n0 + wn + nt * 16 + l15;
      #pragma unroll
      for (int r = 0; r < 4; ++r) {
        const int m = m0 + wm + mt * 16 + q * 4 + r;
        float x = acc[mt][nt][r] + bias[n];

        if (EPI == 0) {
          x = gelu_f(x);
          unsigned short h, l;
          split1(x, h, l);
          Ch[(size_t)m * 1024 + n] = h;
          Cl[(size_t)m * 1024 + n] = l;
        } else if (EPI == 1) {
          int b = m >> 2, s = m & 3;
          int node  = leaf_order[b * 4 + s];
          int nclip = node < 0 ? 0 : node;
          int bs = boundaries[b * 4 + s];
          int bn = (s < 3) ? boundaries[b * 4 + s + 1] : lengths[b];
          bool ok = (node >= 0) && (is_leaf[b * NNODE + nclip] != 0) && (bn - bs > 0);
          float sc = ok ? 1.0f : 0.0f;
          x = (x + dembed[(size_t)depth[nclip] * 1024 + n]) * sc;
          unsigned short h, l;
          split1(x, h, l);
          size_t o = (size_t)(b * NNODE + nclip) * 1024 + n;
          Ch[o] = h; Cl[o] = l;
        } else if (EPI == 2) {
          int mi = m >> 6, b = m & 63;
          int node = mi ? nodeB : nodeA;
          bool ii = (active[b * NNODE + node] != 0) && (is_leaf[b * NNODE + node] == 0);
          float sc = ii ? 1.0f : 0.0f;
          x = (x + dembed[(size_t)depth[node] * 1024 + n]) * sc;
          unsigned short h, l;
          split1(x, h, l);
          size_t o = (size_t)(b * NNODE + node) * 1024 + n;
          Ch[o] = h; Cl[o] = l;
        } else { // EPI == 3
          int b = m & 63;
          bool ii = (active[b * NNODE + 0] != 0) && (is_leaf[b * NNODE + 0] == 0);
          float sc = ii ? 1.0f : 0.0f;
          long long hsh = 0, w = 1;
          #pragma unroll
          for (int i = 0; i < NNODE; ++i) {
            long long p = (long long)active[b * NNODE + i] * 2
                        + (long long)is_leaf[b * NNODE + i];
            hsh += p * w;
            w *= 31;
          }
          long long a = hsh < 0 ? -hsh : hsh;
          int sid = (int)(a % 256);
          x = (x + dembed[(size_t)depth[0] * 1024 + n]) * sc
            + sembed[(size_t)sid * 1024 + n];
          Cf[(size_t)b * 1024 + n] = x;
        }
      }
    }
  }
}

// ---------------------------------------------------------------------------
extern "C" void kernel_launch(void* const* d_in, const int* in_sizes, int n_in,
                              void* d_out, int out_size, void* d_ws, size_t ws_size,
                              hipStream_t stream)
{
  const float* states     = (const float*)d_in[0];
  const int* lengths      = (const int*)d_in[2];
  const int* boundaries   = (const int*)d_in[3];
  const int* leaf_order   = (const int*)d_in[4];
  const int* active       = (const int*)d_in[5];
  const int* is_leaf      = (const int*)d_in[6];
  const int* left_child   = (const int*)d_in[7];
  const int* right_child  = (const int*)d_in[8];
  const int* depth        = (const int*)d_in[9];
  const float* W1  = (const float*)d_in[10];
  const float* b1  = (const float*)d_in[11];
  const float* W2  = (const float*)d_in[12];
  const float* b2  = (const float*)d_in[13];
  const float* Wm1 = (const float*)d_in[14];
  const float* bm1 = (const float*)d_in[15];
  const float* Wm2 = (const float*)d_in[16];
  const float* bm2 = (const float*)d_in[17];
  const float* dembed = (const float*)d_in[18];
  const float* sembed = (const float*)d_in[19];
  float* out = (float*)d_out;

  // workspace carve-up
  char* p = (char*)d_ws;
  float* pooled = (float*)p;                 p += (size_t)256 * 1024 * 4;   // 1 MB
  unsigned short* H1h = (unsigned short*)p;  p += (size_t)256 * 1024 * 2;
  unsigned short* H1l = (unsigned short*)p;  p += (size_t)256 * 1024 * 2;
  unsigned short* Hmh = (unsigned short*)p;  p += (size_t)128 * 1024 * 2;
  unsigned short* Hml = (unsigned short*)p;  p += (size_t)128 * 1024 * 2;
  unsigned short* ndH = (unsigned short*)p;  p += (size_t)NBAT * NNODE * 1024 * 2;
  unsigned short* ndL = (unsigned short*)p;  p += (size_t)NBAT * NNODE * 1024 * 2;
  unsigned short* W1h = (unsigned short*)p;  p += (size_t)1024 * 1024 * 2;
  unsigned short* W1l = (unsigned short*)p;  p += (size_t)1024 * 1024 * 2;
  unsigned short* W2h = (unsigned short*)p;  p += (size_t)1024 * 1024 * 2;
  unsigned short* W2l = (unsigned short*)p;  p += (size_t)1024 * 1024 * 2;
  unsigned short* Wm1h = (unsigned short*)p; p += (size_t)1024 * 2048 * 2;
  unsigned short* Wm1l = (unsigned short*)p; p += (size_t)1024 * 2048 * 2;
  unsigned short* Wm2h = (unsigned short*)p; p += (size_t)1024 * 1024 * 2;
  unsigned short* Wm2l = (unsigned short*)p; p += (size_t)1024 * 1024 * 2;

  hipMemsetAsync(pooled, 0, (size_t)256 * 1024 * 4, stream);

  wprep_kernel<<<dim3(32, 16, 4), 256, 0, stream>>>(
      W1, W2, Wm1, Wm2, W1h, W1l, W2h, W2l, Wm1h, Wm1l, Wm2h, Wm2l);

  pool_kernel<<<dim3(SEQ / TCHUNK, NBAT), 256, 0, stream>>>(
      states, boundaries, lengths, pooled);

  // G1: H1 = gelu(pooled/cnt @ W1 + b1)                 M=256 K=1024
  mfma_gemm<1, 0, 1024><<<dim3(16, 4), 256, 0, stream>>>(
      pooled, nullptr, nullptr, W1h, W1l, b1, H1h, H1l, nullptr,
      boundaries, lengths, leaf_order, active, is_leaf, depth,
      left_child, right_child, dembed, sembed, nullptr, nullptr, -1, -1);

  // G2: leaves -> node planes                           M=256 K=1024
  mfma_gemm<0, 1, 1024><<<dim3(16, 4), 256, 0, stream>>>(
      nullptr, H1h, H1l, W2h, W2l, b2, ndH, ndL, nullptr,
      boundaries, lengths, leaf_order, active, is_leaf, depth,
      left_child, right_child, dembed, sembed, nullptr, nullptr, -1, -1);

  // G3: level-1 merge stage 1 (nodes 1,2)               M=128 K=2048
  mfma_gemm<2, 0, 2048><<<dim3(16, 2), 256, 0, stream>>>(
      nullptr, nullptr, nullptr, Wm1h, Wm1l, bm1, Hmh, Hml, nullptr,
      boundaries, lengths, leaf_order, active, is_leaf, depth,
      left_child, right_child, dembed, sembed, ndH, ndL, 1, 2);

  // G4: level-1 merge stage 2 -> node planes            M=128 K=1024
  mfma_gemm<0, 2, 1024><<<dim3(16, 2), 256, 0, stream>>>(
      nullptr, Hmh, Hml, Wm2h, Wm2l, bm2, ndH, ndL, nullptr,
      boundaries, lengths, leaf_order, active, is_leaf, depth,
      left_child, right_child, dembed, sembed, nullptr, nullptr, 1, 2);

  // G5: root merge stage 1 (node 0)                     M=64 K=2048
  mfma_gemm<2, 0, 2048><<<dim3(16, 1), 256, 0, stream>>>(
      nullptr, nullptr, nullptr, Wm1h, Wm1l, bm1, Hmh, Hml, nullptr,
      boundaries, lengths, leaf_order, active, is_leaf, depth,
      left_child, right_child, dembed, sembed, ndH, ndL, 0, 0);

  // G6: root merge stage 2 + hash + shape_embed -> out  M=64 K=1024
  mfma_gemm<0, 3, 1024><<<dim3(16, 1), 256, 0, stream>>>(
      nullptr, Hmh, Hml, Wm2h, Wm2l, bm2, nullptr, nullptr, out,
      boundaries, lengths, leaf_order, active, is_leaf, depth,
      left_child, right_child, dembed, sembed, nullptr, nullptr, 0, 0);
}